// Round 15
// baseline (305.260 us; speedup 1.0000x reference)
//
#include <hip/hip_runtime.h>
#include <math.h>

#define HW     17600   // 100*176 pixels
#define CD     256     // channels == D
#define LAG    5       // agents
#define NHEAD  8
#define DH     32
#define NT     3       // agent types

typedef short bf16x8 __attribute__((ext_vector_type(8)));
typedef float f32x4  __attribute__((ext_vector_type(4)));

// ---- bf16 helpers ----------------------------------------------------------
__device__ __forceinline__ float bflo(unsigned u) { return __uint_as_float(u << 16); }
__device__ __forceinline__ float bfhi(unsigned u) { return __uint_as_float(u & 0xffff0000u); }
__device__ __forceinline__ unsigned f2bf(float f) {
    unsigned u = __float_as_uint(f);
    return (u + 0x7fffu + ((u >> 16) & 1u)) >> 16;   // RNE
}
__device__ __forceinline__ unsigned pack2(float a, float b) {
    return f2bf(a) | (f2bf(b) << 16);
}

// ---- async global->LDS (16B/lane); dest = wave-uniform base + lane*16 ------
typedef __attribute__((address_space(1))) const unsigned int gu32;
typedef __attribute__((address_space(3))) unsigned int       lu32;
__device__ __forceinline__ void gload_lds16(const void* g, void* l) {
    __builtin_amdgcn_global_load_lds(
        (gu32*)(unsigned long long)(uintptr_t)g,
        (lu32*)(unsigned int)(uintptr_t)l, 16, 0, 0);
}

// ---------------------------------------------------------------------------
// convert_w: W[k][n] fp32 -> Wt[n][k] bf16, 12 matrices (q0..2,k0..2,v0..2,a0..2)
// ---------------------------------------------------------------------------
__global__ __launch_bounds__(256) void convert_w_kernel(
    const float* __restrict__ Wq, const float* __restrict__ Wk,
    const float* __restrict__ Wv, const float* __restrict__ Wa,
    unsigned short* __restrict__ Wt)
{
    __shared__ float tile[64][65];
    const int mat = blockIdx.y;
    const int k0 = (blockIdx.x >> 2) * 64;
    const int n0 = (blockIdx.x & 3) * 64;
    const float* W;
    if      (mat < 3) W = Wq + (long)mat * 65536;
    else if (mat < 6) W = Wk + (long)(mat - 3) * 65536;
    else if (mat < 9) W = Wv + (long)(mat - 6) * 65536;
    else              W = Wa + (long)(mat - 9) * 65536;
    const int t = threadIdx.x;
#pragma unroll
    for (int r = 0; r < 16; ++r) {
        int idx = r * 256 + t;
        int row = idx >> 6, col = idx & 63;
        tile[row][col] = W[(long)(k0 + row) * 256 + n0 + col];
    }
    __syncthreads();
    unsigned short* dst = Wt + (long)mat * 65536;
#pragma unroll
    for (int r = 0; r < 16; ++r) {
        int idx = r * 256 + t;
        int row = idx >> 6, col = idx & 63;
        dst[(long)(n0 + row) * 256 + k0 + col] = (unsigned short)f2bf(tile[col][row]);
    }
}

// ---------------------------------------------------------------------------
// convert_rel: rel_att -> rattT bf16 [9][8][32 q][32 p] (transposed),
//              rel_msg -> rmsgT bf16 [9][8][32 c][32 p] (transposed).
// ---------------------------------------------------------------------------
__global__ __launch_bounds__(256) void convert_rel_kernel(
    const float* __restrict__ rel_att, const float* __restrict__ rel_msg,
    unsigned short* __restrict__ rattT, unsigned short* __restrict__ rmsgT)
{
    const long base = ((long)(blockIdx.x * NHEAD + blockIdx.y)) << 10;
    const int t = threadIdx.x;
#pragma unroll
    for (int i = 0; i < 4; ++i) {
        int idx = t * 4 + i;            // p*32+q
        int p = idx >> 5, q = idx & 31;
        rattT[base + q * 32 + p] = (unsigned short)f2bf(rel_att[base + idx]);
        rmsgT[base + q * 32 + p] = (unsigned short)f2bf(rel_msg[base + idx]);
    }
}

// ---------------------------------------------------------------------------
// GEMM v2: A staged ONCE in LDS (64x256 bf16, 32 KB, XOR-swizzled); W frags
// loaded DIRECTLY from global (L2-resident 128 KB) into VGPRs. Exactly ONE
// __syncthreads in the whole kernel -> waves pipeline freely.
// 256 thr = 4 waves: wr = w>>1 (rows), wc = w&1 (cols).
// ---------------------------------------------------------------------------
__device__ __forceinline__ void gemm_compute_v2(
    const unsigned short* __restrict__ As,   // LDS [64][256] swizzled
    const unsigned short* __restrict__ Wm,   // global [256 n][256 k]
    const float* __restrict__ bias,
    void* __restrict__ Yptr, long ldy, int m0, bool ybf)
{
    const int t  = threadIdx.x;
    const int w  = t >> 6;
    const int l  = t & 63;
    const int wr = w >> 1;
    const int wc = w & 1;
    const int fr = l & 15;
    const int ko = (l >> 4) << 3;
    const int axor = (fr & 7) << 3;

    f32x4 acc[2][8];
#pragma unroll
    for (int i = 0; i < 2; ++i)
#pragma unroll
        for (int j = 0; j < 8; ++j) {
            acc[i][j][0] = 0.f; acc[i][j][1] = 0.f;
            acc[i][j][2] = 0.f; acc[i][j][3] = 0.f;
        }

    for (int ks = 0; ks < 4; ++ks) {
#pragma unroll
        for (int kk = 0; kk < 2; ++kk) {
            const int kbase = (ks << 6) | (kk << 5) | ko;
            const int fcol  = (ks << 6) | (((kk << 5) | ko) ^ axor);
            bf16x8 a[2], b[8];
#pragma unroll
            for (int j = 0; j < 8; ++j)
                b[j] = *(const bf16x8*)(Wm + (long)(wc * 128 + j * 16 + fr) * 256 + kbase);
#pragma unroll
            for (int i = 0; i < 2; ++i)
                a[i] = *(const bf16x8*)(&As[(wr * 32 + i * 16 + fr) * 256 + fcol]);
#pragma unroll
            for (int i = 0; i < 2; ++i)
#pragma unroll
                for (int j = 0; j < 8; ++j)
                    acc[i][j] = __builtin_amdgcn_mfma_f32_16x16x32_bf16(
                        a[i], b[j], acc[i][j], 0, 0, 0);
        }
    }

    const int fq = l >> 4;
#pragma unroll
    for (int j = 0; j < 8; ++j) {
        int col = wc * 128 + j * 16 + fr;
        float bz = bias[col];
#pragma unroll
        for (int i = 0; i < 2; ++i) {
            int rowb = m0 + wr * 32 + i * 16 + (fq << 2);
#pragma unroll
            for (int e = 0; e < 4; ++e) {
                float v = acc[i][j][e] + bz;
                if (ybf)
                    ((unsigned short*)Yptr)[(long)(rowb + e) * ldy + col] =
                        (unsigned short)f2bf(v);
                else
                    ((float*)Yptr)[(long)(rowb + e) * ldy + col] = v;
            }
        }
    }
}

// ---------------------------------------------------------------------------
// Kernel 1: fused q/k/v projections. grid (275, 1, 5).
// x panel (fp32) converted+staged once -> 3 projections computed barrier-free.
// q -> [pix][5][256]; k,v -> [l][pix][256].
// ---------------------------------------------------------------------------
__global__ __launch_bounds__(256) void gemm_qkv_mfma(
    const float* __restrict__ x, const float* __restrict__ pe,
    const unsigned short* __restrict__ Wt,
    const float* __restrict__ bq, const float* __restrict__ bk,
    const float* __restrict__ bv,
    unsigned short* __restrict__ qws, unsigned short* __restrict__ kws,
    unsigned short* __restrict__ vws)
{
    __shared__ unsigned short As[64 * 256];   // 32 KB

    const int t   = threadIdx.x;
    const int m0  = blockIdx.x * 64;
    const int lag = blockIdx.z;
    const int tpe = (int)pe[lag * 3 + 2];
    const float* A = x + (long)lag * HW * CD;

    // stage A once: 8 rounds, fp32 -> bf16, swizzled store
#pragma unroll
    for (int r = 0; r < 8; ++r) {
        int idx  = r * 256 + t;
        int row  = idx >> 5;
        int colg = (idx & 31) << 3;
        int scol = colg ^ ((row & 7) << 3);
        const float* src = A + (long)(m0 + row) * CD + colg;
        float4 f0 = *(const float4*)src;
        float4 f1 = *(const float4*)(src + 4);
        uint4 u;
        u.x = pack2(f0.x, f0.y); u.y = pack2(f0.z, f0.w);
        u.z = pack2(f1.x, f1.y); u.w = pack2(f1.z, f1.w);
        *(uint4*)(&As[row * 256 + scol]) = u;
    }
    __syncthreads();

#pragma unroll 1
    for (int proj = 0; proj < 3; ++proj) {
        const unsigned short* Wm = Wt + (long)(proj * 3 + tpe) * 65536;
        const float* bias;
        unsigned short* Y;
        long ldy;
        if      (proj == 0) { bias = bq; Y = qws + (long)lag * CD; ldy = LAG * CD; }
        else if (proj == 1) { bias = bk; Y = kws + (long)lag * HW * CD; ldy = CD; }
        else                { bias = bv; Y = vws + (long)lag * HW * CD; ldy = CD; }
        bias += tpe * CD;
        gemm_compute_v2(As, Wm, bias, Y, ldy, m0, true);
    }
}

// ---------------------------------------------------------------------------
// Kernel 3: output projection. grid (275, 1, 5). A = aws [pix][5][256] bf16.
// A staged once via global_load_lds (pre-swizzled source), W direct-global.
// ---------------------------------------------------------------------------
__global__ __launch_bounds__(256) void gemm_out_mfma(
    const unsigned short* __restrict__ aws, const float* __restrict__ pe,
    const unsigned short* __restrict__ Wt, const float* __restrict__ ba,
    float* __restrict__ out)
{
    __shared__ unsigned short As[64 * 256];   // 32 KB

    const int t   = threadIdx.x;
    const int m0  = blockIdx.x * 64;
    const int lag = blockIdx.z;
    const int tpe = (int)pe[lag * 3 + 2];
    const unsigned short* A = aws + (long)lag * CD;   // row stride 1280

    // stage A once: 8 rounds of global_load_lds; LDS dest linear = idx*16B,
    // source column pre-swizzled so the XOR-on-read below stays valid.
#pragma unroll
    for (int r = 0; r < 8; ++r) {
        int idx  = r * 256 + t;
        int row  = idx >> 5;
        int colg = (idx & 31) << 3;
        int scol = colg ^ ((row & 7) << 3);
        const unsigned short* src = A + (long)(m0 + row) * (LAG * CD) + scol;
        gload_lds16(src, &As[idx * 8]);
    }
    __syncthreads();

    const unsigned short* Wm = Wt + (long)(9 + tpe) * 65536;
    const float* bias = ba + tpe * CD;
    float* Y = out + (long)lag * HW * CD;
    gemm_compute_v2(As, Wm, bias, Y, CD, m0, false);
}

// ---------------------------------------------------------------------------
// Kernel 2 (FUSED attention v5 = v1 + bpermute phase-3): unchanged, best-known.
// ---------------------------------------------------------------------------
#define QTROW 488   // 5*3*32 = 480 + 8 pad (2-way banks)

__global__ __launch_bounds__(256) void attn_fused_kernel(
    const unsigned short* __restrict__ qws,    // [pix][5][256]
    const unsigned short* __restrict__ kws,    // [j][pix][256]
    const unsigned short* __restrict__ vws,    // [j][pix][256]
    const unsigned short* __restrict__ rattT,  // [9][8][32 q][32 p]
    const unsigned short* __restrict__ rmsgT,  // [9][8][32 c][32 p]
    const int* __restrict__ mask, const float* __restrict__ pe,
    unsigned short* __restrict__ aws)          // [pix][5][256]
{
    __shared__ unsigned short lds[4 * 16 * QTROW];   // 62.5 KB

    const int t    = threadIdx.x;
    const int w    = t >> 6;
    const int l    = t & 63;
    const int fr   = l & 15;
    const int fq   = l >> 4;
    const int m    = blockIdx.y;
    const int pix0 = blockIdx.x * 64;

    const int pl2   = t >> 2;          // 0..63 local pixel
    const int sub   = t & 3;           // q/p octet
    const int gpix2 = pix0 + pl2;

    int ty[LAG];
#pragma unroll
    for (int i = 0; i < LAG; ++i) ty[i] = (int)pe[i * 3 + 2];
    bool pres[NT] = {false, false, false};
#pragma unroll
    for (int i = 0; i < LAG; ++i) {
        pres[0] = pres[0] || (ty[i] == 0);
        pres[1] = pres[1] || (ty[i] == 1);
        pres[2] = pres[2] || (ty[i] == 2);
    }

    // ---- early global loads (k, v, mask) for MLP --------------------------
    uint4 kf[LAG], vf[LAG];
    int mk[LAG];
#pragma unroll
    for (int j = 0; j < LAG; ++j) {
        const long off = ((long)j * HW + gpix2) * CD + m * DH + sub * 8;
        kf[j] = *(const uint4*)(kws + off);
        vf[j] = *(const uint4*)(vws + off);
        mk[j] = mask[gpix2 * LAG + j];
    }

    // ---- phase 1: qt via MFMA ---------------------------------------------
    {
        bf16x8 aq[LAG];
#pragma unroll
        for (int i = 0; i < LAG; ++i)
            aq[i] = *(const bf16x8*)(qws + (long)(pix0 + w * 16 + fr) * (LAG * CD)
                                     + i * CD + m * DH + fq * 8);
        const int qtbase = w * 16 * QTROW;
#pragma unroll
        for (int sg = 0; sg < NT; ++sg) {
            if (!pres[sg]) continue;
#pragma unroll
            for (int i = 0; i < LAG; ++i) {
                const int e = ty[i] * NT + sg;
                const unsigned short* bb = rattT + ((long)(e * NHEAD + m) << 10);
                bf16x8 b0 = *(const bf16x8*)(bb + fr * 32 + fq * 8);
                bf16x8 b1 = *(const bf16x8*)(bb + (fr + 16) * 32 + fq * 8);
                f32x4 z = {0.f, 0.f, 0.f, 0.f};
                f32x4 d0 = __builtin_amdgcn_mfma_f32_16x16x32_bf16(aq[i], b0, z, 0, 0, 0);
                f32x4 d1 = __builtin_amdgcn_mfma_f32_16x16x32_bf16(aq[i], b1, z, 0, 0, 0);
#pragma unroll
                for (int e4 = 0; e4 < 4; ++e4) {
                    const int idx = qtbase + (fq * 4 + e4) * QTROW + (i * NT + sg) * 32;
                    lds[idx + fr]      = (unsigned short)f2bf(d0[e4]);
                    lds[idx + fr + 16] = (unsigned short)f2bf(d1[e4]);
                }
            }
        }
    }
    __syncthreads();

    // ---- phase 2: logits + softmax -----------------------------------------
    const float scale = 0.17677669529663687f;  // 32^-0.5
    float att[LAG][LAG];
    {
        const int qtb = w * 16 * QTROW + (pl2 & 15) * QTROW;
#pragma unroll
        for (int j = 0; j < LAG; ++j) {
            float kx[8];
            kx[0] = bflo(kf[j].x); kx[1] = bfhi(kf[j].x);
            kx[2] = bflo(kf[j].y); kx[3] = bfhi(kf[j].y);
            kx[4] = bflo(kf[j].z); kx[5] = bfhi(kf[j].z);
            kx[6] = bflo(kf[j].w); kx[7] = bfhi(kf[j].w);
            const int tyj = ty[j];
#pragma unroll
            for (int i = 0; i < LAG; ++i) {
                uint4 qv = *(const uint4*)(&lds[qtb + (i * NT + tyj) * 32 + sub * 8]);
                float part;
                part = bflo(qv.x) * kx[0];
                part = fmaf(bfhi(qv.x), kx[1], part);
                part = fmaf(bflo(qv.y), kx[2], part);
                part = fmaf(bfhi(qv.y), kx[3], part);
                part = fmaf(bflo(qv.z), kx[4], part);
                part = fmaf(bfhi(qv.z), kx[5], part);
                part = fmaf(bflo(qv.w), kx[6], part);
                part = fmaf(bfhi(qv.w), kx[7], part);
                part += __shfl_xor(part, 1);
                part += __shfl_xor(part, 2);
                att[i][j] = part * scale;
            }
        }
#pragma unroll
        for (int i = 0; i < LAG; ++i) {
            float mx = -INFINITY;
#pragma unroll
            for (int j = 0; j < LAG; ++j) {
                att[i][j] = mk[j] ? att[i][j] : -INFINITY;
                mx = fmaxf(mx, att[i][j]);
            }
            float ssum = 0.f;
#pragma unroll
            for (int j = 0; j < LAG; ++j) {
                att[i][j] = __expf(att[i][j] - mx);
                ssum += att[i][j];
            }
            float inv = 1.f / ssum;
#pragma unroll
            for (int j = 0; j < LAG; ++j) att[i][j] *= inv;
        }
    }

    // unpack v once
    float vx[LAG][8];
#pragma unroll
    for (int j = 0; j < LAG; ++j) {
        vx[j][0] = bflo(vf[j].x); vx[j][1] = bfhi(vf[j].x);
        vx[j][2] = bflo(vf[j].y); vx[j][3] = bfhi(vf[j].y);
        vx[j][4] = bflo(vf[j].z); vx[j][5] = bfhi(vf[j].z);
        vx[j][6] = bflo(vf[j].w); vx[j][7] = bfhi(vf[j].w);
    }

    // ---- phase 3: vagg -> ds_bpermute redistribution -> MFMA ---------------
    f32x4 oacc[LAG][2];
#pragma unroll
    for (int i = 0; i < LAG; ++i)
#pragma unroll
        for (int c = 0; c < 2; ++c) {
            oacc[i][c][0] = 0.f; oacc[i][c][1] = 0.f;
            oacc[i][c][2] = 0.f; oacc[i][c][3] = 0.f;
        }

    const int baddr = (((l & 15) << 2) | (l >> 4)) << 2;

#pragma unroll
    for (int sg = 0; sg < NT; ++sg) {
        if (!pres[sg]) continue;
#pragma unroll
        for (int i = 0; i < LAG; ++i) {
            float vg[8] = {0.f,0.f,0.f,0.f,0.f,0.f,0.f,0.f};
#pragma unroll
            for (int j = 0; j < LAG; ++j) {
                float wj = (ty[j] == sg) ? att[i][j] : 0.f;
#pragma unroll
                for (int d = 0; d < 8; ++d) vg[d] = fmaf(wj, vx[j][d], vg[d]);
            }
            int p0 = (int)pack2(vg[0], vg[1]);
            int p1 = (int)pack2(vg[2], vg[3]);
            int p2 = (int)pack2(vg[4], vg[5]);
            int p3 = (int)pack2(vg[6], vg[7]);
            int r0 = __builtin_amdgcn_ds_bpermute(baddr, p0);
            int r1 = __builtin_amdgcn_ds_bpermute(baddr, p1);
            int r2 = __builtin_amdgcn_ds_bpermute(baddr, p2);
            int r3 = __builtin_amdgcn_ds_bpermute(baddr, p3);
            int av[4] = {r0, r1, r2, r3};
            bf16x8 a = *(const bf16x8*)av;

            const int e = ty[i] * NT + sg;
            const unsigned short* bb = rmsgT + ((long)(e * NHEAD + m) << 10);
            bf16x8 b0 = *(const bf16x8*)(bb + fr * 32 + fq * 8);
            bf16x8 b1 = *(const bf16x8*)(bb + (fr + 16) * 32 + fq * 8);
            oacc[i][0] = __builtin_amdgcn_mfma_f32_16x16x32_bf16(a, b0, oacc[i][0], 0, 0, 0);
            oacc[i][1] = __builtin_amdgcn_mfma_f32_16x16x32_bf16(a, b1, oacc[i][1], 0, 0, 0);
        }
    }

    // ---- store: lane holds out[pix=fq*4+e][c=fr, fr+16] --------------------
#pragma unroll
    for (int i = 0; i < LAG; ++i) {
#pragma unroll
        for (int e4 = 0; e4 < 4; ++e4) {
            const long ob = (long)(pix0 + w * 16 + fq * 4 + e4) * (LAG * CD)
                            + i * CD + m * DH;
            aws[ob + fr]      = (unsigned short)f2bf(oacc[i][0][e4]);
            aws[ob + fr + 16] = (unsigned short)f2bf(oacc[i][1][e4]);
        }
    }
}

// ---------------------------------------------------------------------------
extern "C" void kernel_launch(void* const* d_in, const int* in_sizes, int n_in,
                              void* d_out, int out_size, void* d_ws, size_t ws_size,
                              hipStream_t stream) {
    const float* x    = (const float*)d_in[0];
    const int*   mask = (const int*)  d_in[1];
    const float* pe   = (const float*)d_in[2];
    const float* Wq   = (const float*)d_in[3];
    const float* bq   = (const float*)d_in[4];
    const float* Wk   = (const float*)d_in[5];
    const float* bk   = (const float*)d_in[6];
    const float* Wv   = (const float*)d_in[7];
    const float* bv   = (const float*)d_in[8];
    const float* Wa   = (const float*)d_in[9];
    const float* ba   = (const float*)d_in[10];
    const float* ratt = (const float*)d_in[11];
    const float* rmsg = (const float*)d_in[12];
    float* out = (float*)d_out;

    const size_t PLANE = (size_t)LAG * HW * CD;   // 22,528,000 elems

    unsigned short* qws   = (unsigned short*)d_ws;          // [pix][5][256]
    unsigned short* kws   = qws + PLANE;                    // [5][pix][256]
    unsigned short* vws   = kws + PLANE;
    unsigned short* aws   = vws + PLANE;                    // [pix][5][256]
    unsigned short* Wt    = aws + PLANE;    // 786,432 elems
    unsigned short* rattT = Wt + 786432;    // 73,728 elems
    unsigned short* rmsgT = rattT + 73728;  // 73,728 elems
    // total ~182 MB

    convert_w_kernel<<<dim3(16, 12), 256, 0, stream>>>(Wq, Wk, Wv, Wa, Wt);
    convert_rel_kernel<<<dim3(9, 8), 256, 0, stream>>>(ratt, rmsg, rattT, rmsgT);

    gemm_qkv_mfma<<<dim3(HW / 64, 1, LAG), 256, 0, stream>>>(
        x, pe, Wt, bq, bk, bv, qws, kws, vws);

    attn_fused_kernel<<<dim3(HW / 64, NHEAD), 256, 0, stream>>>(
        qws, kws, vws, rattT, rmsgT, mask, pe, aws);

    gemm_out_mfma<<<dim3(HW / 64, 1, LAG), 256, 0, stream>>>(aws, pe, Wt, ba, out);
}

// Round 16
// 186.095 us; speedup vs baseline: 1.6403x; 1.6403x over previous
//
#include <hip/hip_runtime.h>
#include <math.h>

#define HW     17600   // 100*176 pixels
#define CD     256     // channels == D
#define LAG    5       // agents
#define NHEAD  8
#define DH     32
#define NT     3       // agent types

typedef short bf16x8 __attribute__((ext_vector_type(8)));
typedef float f32x4  __attribute__((ext_vector_type(4)));

// ---- bf16 helpers ----------------------------------------------------------
__device__ __forceinline__ float bflo(unsigned u) { return __uint_as_float(u << 16); }
__device__ __forceinline__ float bfhi(unsigned u) { return __uint_as_float(u & 0xffff0000u); }
__device__ __forceinline__ unsigned f2bf(float f) {
    unsigned u = __float_as_uint(f);
    return (u + 0x7fffu + ((u >> 16) & 1u)) >> 16;   // RNE
}
__device__ __forceinline__ unsigned pack2(float a, float b) {
    return f2bf(a) | (f2bf(b) << 16);
}

// ---- async global->LDS (16B/lane); dest = wave-uniform base + lane*16 ------
typedef __attribute__((address_space(1))) const unsigned int gu32;
typedef __attribute__((address_space(3))) unsigned int       lu32;
__device__ __forceinline__ void gload_lds16(const void* g, void* l) {
    __builtin_amdgcn_global_load_lds(
        (gu32*)(unsigned long long)(uintptr_t)g,
        (lu32*)(unsigned int)(uintptr_t)l, 16, 0, 0);
}

// ---------------------------------------------------------------------------
// convert_w: W[k][n] fp32 -> Wt[n][k] bf16, 12 matrices (q0..2,k0..2,v0..2,a0..2)
// ---------------------------------------------------------------------------
__global__ __launch_bounds__(256) void convert_w_kernel(
    const float* __restrict__ Wq, const float* __restrict__ Wk,
    const float* __restrict__ Wv, const float* __restrict__ Wa,
    unsigned short* __restrict__ Wt)
{
    __shared__ float tile[64][65];
    const int mat = blockIdx.y;
    const int k0 = (blockIdx.x >> 2) * 64;
    const int n0 = (blockIdx.x & 3) * 64;
    const float* W;
    if      (mat < 3) W = Wq + (long)mat * 65536;
    else if (mat < 6) W = Wk + (long)(mat - 3) * 65536;
    else if (mat < 9) W = Wv + (long)(mat - 6) * 65536;
    else              W = Wa + (long)(mat - 9) * 65536;
    const int t = threadIdx.x;
#pragma unroll
    for (int r = 0; r < 16; ++r) {
        int idx = r * 256 + t;
        int row = idx >> 6, col = idx & 63;
        tile[row][col] = W[(long)(k0 + row) * 256 + n0 + col];
    }
    __syncthreads();
    unsigned short* dst = Wt + (long)mat * 65536;
#pragma unroll
    for (int r = 0; r < 16; ++r) {
        int idx = r * 256 + t;
        int row = idx >> 6, col = idx & 63;
        dst[(long)(n0 + row) * 256 + k0 + col] = (unsigned short)f2bf(tile[col][row]);
    }
}

// ---------------------------------------------------------------------------
// convert_rel: rel_att -> rattT bf16 [9][8][32 q][32 p] (transposed),
//              rel_msg -> rmsgT bf16 [9][8][32 c][32 p] (transposed).
// ---------------------------------------------------------------------------
__global__ __launch_bounds__(256) void convert_rel_kernel(
    const float* __restrict__ rel_att, const float* __restrict__ rel_msg,
    unsigned short* __restrict__ rattT, unsigned short* __restrict__ rmsgT)
{
    const long base = ((long)(blockIdx.x * NHEAD + blockIdx.y)) << 10;
    const int t = threadIdx.x;
#pragma unroll
    for (int i = 0; i < 4; ++i) {
        int idx = t * 4 + i;            // p*32+q
        int p = idx >> 5, q = idx & 31;
        rattT[base + q * 32 + p] = (unsigned short)f2bf(rel_att[base + idx]);
        rmsgT[base + q * 32 + p] = (unsigned short)f2bf(rel_msg[base + idx]);
    }
}

// ---------------------------------------------------------------------------
// MFMA GEMM core (64-row tile): Y[64 x 256] = A @ Wt^T + bias.
// 256 threads = 4 waves. Staging via global_load_lds (16B) with PRE-SWIZZLED
// global source; LDS dest linear. A path: fp32 (qkv) VGPR-convert staging;
// bf16 (out) gload_lds. XOR swizzle col ^= (row&7)<<3 on store + frag read.
// Measured best GEMM structure (rounds 12-15 A/B).
// ---------------------------------------------------------------------------
template<bool AF32, bool YBF>
__device__ __forceinline__ void gemm_mfma_core(
    const void* __restrict__ Aptr, long lda,
    const unsigned short* __restrict__ Wt,
    const float* __restrict__ bias,
    void* __restrict__ Yptr, long ldy)
{
    __shared__ unsigned short As[64 * 64];
    __shared__ unsigned short Ws[256 * 64];

    const int t  = threadIdx.x;
    const int m0 = blockIdx.x * 64;
    const int w  = t >> 6;
    const int l  = t & 63;
    const int wr = w >> 1;
    const int wc = w & 1;
    const int fr = l & 15;
    const int ko = (l >> 4) << 3;

    const int srow = t >> 3;                      // 0..31 within a round
    const int colu = (t & 7) << 3;
    const int axor = (fr & 7) << 3;

    f32x4 acc[2][8];
#pragma unroll
    for (int i = 0; i < 2; ++i)
#pragma unroll
        for (int j = 0; j < 8; ++j) {
            acc[i][j][0] = 0.f; acc[i][j][1] = 0.f;
            acc[i][j][2] = 0.f; acc[i][j][3] = 0.f;
        }

    for (int ks = 0; ks < 4; ++ks) {
        const int k0 = ks << 6;
        __syncthreads();
        // ---- stage A: 64 rows x 64 cols, 2 rounds -------------------------
#pragma unroll
        for (int r = 0; r < 2; ++r) {
            const int row  = r * 32 + srow;
            const int xr   = (row & 7) << 3;
            const int scol = colu ^ xr;
            if (AF32) {
                const float* src = (const float*)Aptr + (long)(m0 + row) * lda + k0 + colu;
                float4 f0 = *(const float4*)src;
                float4 f1 = *(const float4*)(src + 4);
                uint4 u;
                u.x = pack2(f0.x, f0.y); u.y = pack2(f0.z, f0.w);
                u.z = pack2(f1.x, f1.y); u.w = pack2(f1.z, f1.w);
                *(uint4*)(&As[row * 64 + scol]) = u;
            } else {
                const unsigned short* src =
                    (const unsigned short*)Aptr + (long)(m0 + row) * lda + k0 + scol;
                gload_lds16(src, &As[r * 2048 + w * 512]);
            }
        }
        // ---- stage Wt: 256 rows x 64 cols, 8 rounds, async ----------------
#pragma unroll
        for (int r = 0; r < 8; ++r) {
            const int row  = r * 32 + srow;
            const int scol = colu ^ ((row & 7) << 3);
            const unsigned short* src = Wt + (long)row * 256 + k0 + scol;
            gload_lds16(src, &Ws[r * 2048 + w * 512]);
        }
        __syncthreads();   // drains vmcnt (incl. global_load_lds) + lgkmcnt
#pragma unroll
        for (int kk = 0; kk < 2; ++kk) {
            const int fcol = ((kk << 5) | ko) ^ axor;
            bf16x8 a[2], b[8];
#pragma unroll
            for (int i = 0; i < 2; ++i)
                a[i] = *(const bf16x8*)(&As[(wr * 32 + i * 16 + fr) * 64 + fcol]);
#pragma unroll
            for (int j = 0; j < 8; ++j)
                b[j] = *(const bf16x8*)(&Ws[(wc * 128 + j * 16 + fr) * 64 + fcol]);
#pragma unroll
            for (int i = 0; i < 2; ++i)
#pragma unroll
                for (int j = 0; j < 8; ++j)
                    acc[i][j] = __builtin_amdgcn_mfma_f32_16x16x32_bf16(
                        a[i], b[j], acc[i][j], 0, 0, 0);
        }
    }

    const int fq = l >> 4;
#pragma unroll
    for (int j = 0; j < 8; ++j) {
        int col = wc * 128 + j * 16 + fr;
        float bz = bias[col];
#pragma unroll
        for (int i = 0; i < 2; ++i) {
            int rowb = m0 + wr * 32 + i * 16 + (fq << 2);
#pragma unroll
            for (int e = 0; e < 4; ++e) {
                float v = acc[i][j][e] + bz;
                if (YBF)
                    ((unsigned short*)Yptr)[(long)(rowb + e) * ldy + col] =
                        (unsigned short)f2bf(v);
                else
                    ((float*)Yptr)[(long)(rowb + e) * ldy + col] = v;
            }
        }
    }
}

// ---------------------------------------------------------------------------
// Kernel 1: fused q/k/v projections. grid (275, 1, 5); proj loop in-block
// (x panel L2-hot for 2nd/3rd pass). q -> [pix][5][256]; k,v -> [l][pix][256].
// ---------------------------------------------------------------------------
__global__ __launch_bounds__(256) void gemm_qkv_mfma(
    const float* __restrict__ x, const float* __restrict__ pe,
    const unsigned short* __restrict__ Wt,
    const float* __restrict__ bq, const float* __restrict__ bk,
    const float* __restrict__ bv,
    unsigned short* __restrict__ qws, unsigned short* __restrict__ kws,
    unsigned short* __restrict__ vws)
{
    const int lag = blockIdx.z;
    const int tpe = (int)pe[lag * 3 + 2];
    const float* A = x + (long)lag * HW * CD;

#pragma unroll 1
    for (int proj = 0; proj < 3; ++proj) {
        const unsigned short* Wm = Wt + (long)(proj * 3 + tpe) * 65536;
        const float* bias;
        unsigned short* Y;
        long ldy;
        if      (proj == 0) { bias = bq; Y = qws + (long)lag * CD; ldy = LAG * CD; }
        else if (proj == 1) { bias = bk; Y = kws + (long)lag * HW * CD; ldy = CD; }
        else                { bias = bv; Y = vws + (long)lag * HW * CD; ldy = CD; }
        bias += tpe * CD;
        gemm_mfma_core<true, true>(A, CD, Wm, bias, Y, ldy);
        __syncthreads();
    }
}

// ---------------------------------------------------------------------------
// Kernel 3: output projection. grid (275, 1, 5). A = aws [pix][5][256].
// ---------------------------------------------------------------------------
__global__ __launch_bounds__(256) void gemm_out_mfma(
    const unsigned short* __restrict__ aws, const float* __restrict__ pe,
    const unsigned short* __restrict__ Wt, const float* __restrict__ ba,
    float* __restrict__ out)
{
    const int lag = blockIdx.z;
    const int tpe = (int)pe[lag * 3 + 2];
    const unsigned short* A = aws + (long)lag * CD;
    const unsigned short* Wm = Wt + (long)(9 + tpe) * 65536;
    const float* bias = ba + tpe * CD;
    float* Y = out + (long)lag * HW * CD;
    gemm_mfma_core<false, false>(A, (long)LAG * CD, Wm, bias, Y, CD);
}

// ---------------------------------------------------------------------------
// Kernel 2 (FUSED attention v5 = v1 + bpermute phase-3): measured best.
// block = 64 pixels x 1 head, 256 thr = 4 waves.
// Phase 1: qt[i][sigma] for ALL sigma via MFMA -> LDS (row 488). One barrier.
// Phase 2: logits (8-FMA dots + quad shfl), masked softmax in registers.
// Phase 3: vagg -> A-frag redistribution via 4x ds_bpermute (fixed intra-wave
//   permutation src = ((l&15)<<2)|(l>>4)) -> MFMA rmsgT. NO LDS, NO barriers.
// ---------------------------------------------------------------------------
#define QTROW 488   // 5*3*32 = 480 + 8 pad (2-way banks)

__global__ __launch_bounds__(256) void attn_fused_kernel(
    const unsigned short* __restrict__ qws,    // [pix][5][256]
    const unsigned short* __restrict__ kws,    // [j][pix][256]
    const unsigned short* __restrict__ vws,    // [j][pix][256]
    const unsigned short* __restrict__ rattT,  // [9][8][32 q][32 p]
    const unsigned short* __restrict__ rmsgT,  // [9][8][32 c][32 p]
    const int* __restrict__ mask, const float* __restrict__ pe,
    unsigned short* __restrict__ aws)          // [pix][5][256]
{
    __shared__ unsigned short lds[4 * 16 * QTROW];   // 62.5 KB

    const int t    = threadIdx.x;
    const int w    = t >> 6;
    const int l    = t & 63;
    const int fr   = l & 15;
    const int fq   = l >> 4;
    const int m    = blockIdx.y;
    const int pix0 = blockIdx.x * 64;

    const int pl2   = t >> 2;          // 0..63 local pixel
    const int sub   = t & 3;           // q/p octet
    const int gpix2 = pix0 + pl2;

    int ty[LAG];
#pragma unroll
    for (int i = 0; i < LAG; ++i) ty[i] = (int)pe[i * 3 + 2];
    bool pres[NT] = {false, false, false};
#pragma unroll
    for (int i = 0; i < LAG; ++i) {
        pres[0] = pres[0] || (ty[i] == 0);
        pres[1] = pres[1] || (ty[i] == 1);
        pres[2] = pres[2] || (ty[i] == 2);
    }

    // ---- early global loads (k, v, mask) for MLP --------------------------
    uint4 kf[LAG], vf[LAG];
    int mk[LAG];
#pragma unroll
    for (int j = 0; j < LAG; ++j) {
        const long off = ((long)j * HW + gpix2) * CD + m * DH + sub * 8;
        kf[j] = *(const uint4*)(kws + off);
        vf[j] = *(const uint4*)(vws + off);
        mk[j] = mask[gpix2 * LAG + j];
    }

    // ---- phase 1: qt via MFMA ---------------------------------------------
    {
        bf16x8 aq[LAG];
#pragma unroll
        for (int i = 0; i < LAG; ++i)
            aq[i] = *(const bf16x8*)(qws + (long)(pix0 + w * 16 + fr) * (LAG * CD)
                                     + i * CD + m * DH + fq * 8);
        const int qtbase = w * 16 * QTROW;
#pragma unroll
        for (int sg = 0; sg < NT; ++sg) {
            if (!pres[sg]) continue;
#pragma unroll
            for (int i = 0; i < LAG; ++i) {
                const int e = ty[i] * NT + sg;
                const unsigned short* bb = rattT + ((long)(e * NHEAD + m) << 10);
                bf16x8 b0 = *(const bf16x8*)(bb + fr * 32 + fq * 8);
                bf16x8 b1 = *(const bf16x8*)(bb + (fr + 16) * 32 + fq * 8);
                f32x4 z = {0.f, 0.f, 0.f, 0.f};
                f32x4 d0 = __builtin_amdgcn_mfma_f32_16x16x32_bf16(aq[i], b0, z, 0, 0, 0);
                f32x4 d1 = __builtin_amdgcn_mfma_f32_16x16x32_bf16(aq[i], b1, z, 0, 0, 0);
#pragma unroll
                for (int e4 = 0; e4 < 4; ++e4) {
                    const int idx = qtbase + (fq * 4 + e4) * QTROW + (i * NT + sg) * 32;
                    lds[idx + fr]      = (unsigned short)f2bf(d0[e4]);
                    lds[idx + fr + 16] = (unsigned short)f2bf(d1[e4]);
                }
            }
        }
    }
    __syncthreads();

    // ---- phase 2: logits + softmax -----------------------------------------
    const float scale = 0.17677669529663687f;  // 32^-0.5
    float att[LAG][LAG];
    {
        const int qtb = w * 16 * QTROW + (pl2 & 15) * QTROW;
#pragma unroll
        for (int j = 0; j < LAG; ++j) {
            float kx[8];
            kx[0] = bflo(kf[j].x); kx[1] = bfhi(kf[j].x);
            kx[2] = bflo(kf[j].y); kx[3] = bfhi(kf[j].y);
            kx[4] = bflo(kf[j].z); kx[5] = bfhi(kf[j].z);
            kx[6] = bflo(kf[j].w); kx[7] = bfhi(kf[j].w);
            const int tyj = ty[j];
#pragma unroll
            for (int i = 0; i < LAG; ++i) {
                uint4 qv = *(const uint4*)(&lds[qtb + (i * NT + tyj) * 32 + sub * 8]);
                float part;
                part = bflo(qv.x) * kx[0];
                part = fmaf(bfhi(qv.x), kx[1], part);
                part = fmaf(bflo(qv.y), kx[2], part);
                part = fmaf(bfhi(qv.y), kx[3], part);
                part = fmaf(bflo(qv.z), kx[4], part);
                part = fmaf(bfhi(qv.z), kx[5], part);
                part = fmaf(bflo(qv.w), kx[6], part);
                part = fmaf(bfhi(qv.w), kx[7], part);
                part += __shfl_xor(part, 1);
                part += __shfl_xor(part, 2);
                att[i][j] = part * scale;
            }
        }
#pragma unroll
        for (int i = 0; i < LAG; ++i) {
            float mx = -INFINITY;
#pragma unroll
            for (int j = 0; j < LAG; ++j) {
                att[i][j] = mk[j] ? att[i][j] : -INFINITY;
                mx = fmaxf(mx, att[i][j]);
            }
            float ssum = 0.f;
#pragma unroll
            for (int j = 0; j < LAG; ++j) {
                att[i][j] = __expf(att[i][j] - mx);
                ssum += att[i][j];
            }
            float inv = 1.f / ssum;
#pragma unroll
            for (int j = 0; j < LAG; ++j) att[i][j] *= inv;
        }
    }

    // unpack v once
    float vx[LAG][8];
#pragma unroll
    for (int j = 0; j < LAG; ++j) {
        vx[j][0] = bflo(vf[j].x); vx[j][1] = bfhi(vf[j].x);
        vx[j][2] = bflo(vf[j].y); vx[j][3] = bfhi(vf[j].y);
        vx[j][4] = bflo(vf[j].z); vx[j][5] = bfhi(vf[j].z);
        vx[j][6] = bflo(vf[j].w); vx[j][7] = bfhi(vf[j].w);
    }

    // ---- phase 3: vagg -> ds_bpermute redistribution -> MFMA ---------------
    f32x4 oacc[LAG][2];
#pragma unroll
    for (int i = 0; i < LAG; ++i)
#pragma unroll
        for (int c = 0; c < 2; ++c) {
            oacc[i][c][0] = 0.f; oacc[i][c][1] = 0.f;
            oacc[i][c][2] = 0.f; oacc[i][c][3] = 0.f;
        }

    const int baddr = (((l & 15) << 2) | (l >> 4)) << 2;

#pragma unroll
    for (int sg = 0; sg < NT; ++sg) {
        if (!pres[sg]) continue;
#pragma unroll
        for (int i = 0; i < LAG; ++i) {
            float vg[8] = {0.f,0.f,0.f,0.f,0.f,0.f,0.f,0.f};
#pragma unroll
            for (int j = 0; j < LAG; ++j) {
                float wj = (ty[j] == sg) ? att[i][j] : 0.f;
#pragma unroll
                for (int d = 0; d < 8; ++d) vg[d] = fmaf(wj, vx[j][d], vg[d]);
            }
            int p0 = (int)pack2(vg[0], vg[1]);
            int p1 = (int)pack2(vg[2], vg[3]);
            int p2 = (int)pack2(vg[4], vg[5]);
            int p3 = (int)pack2(vg[6], vg[7]);
            int r0 = __builtin_amdgcn_ds_bpermute(baddr, p0);
            int r1 = __builtin_amdgcn_ds_bpermute(baddr, p1);
            int r2 = __builtin_amdgcn_ds_bpermute(baddr, p2);
            int r3 = __builtin_amdgcn_ds_bpermute(baddr, p3);
            int av[4] = {r0, r1, r2, r3};
            bf16x8 a = *(const bf16x8*)av;

            const int e = ty[i] * NT + sg;
            const unsigned short* bb = rmsgT + ((long)(e * NHEAD + m) << 10);
            bf16x8 b0 = *(const bf16x8*)(bb + fr * 32 + fq * 8);
            bf16x8 b1 = *(const bf16x8*)(bb + (fr + 16) * 32 + fq * 8);
            oacc[i][0] = __builtin_amdgcn_mfma_f32_16x16x32_bf16(a, b0, oacc[i][0], 0, 0, 0);
            oacc[i][1] = __builtin_amdgcn_mfma_f32_16x16x32_bf16(a, b1, oacc[i][1], 0, 0, 0);
        }
    }

    // ---- store: lane holds out[pix=fq*4+e][c=fr, fr+16] --------------------
#pragma unroll
    for (int i = 0; i < LAG; ++i) {
#pragma unroll
        for (int e4 = 0; e4 < 4; ++e4) {
            const long ob = (long)(pix0 + w * 16 + fq * 4 + e4) * (LAG * CD)
                            + i * CD + m * DH;
            aws[ob + fr]      = (unsigned short)f2bf(oacc[i][0][e4]);
            aws[ob + fr + 16] = (unsigned short)f2bf(oacc[i][1][e4]);
        }
    }
}

// ---------------------------------------------------------------------------
extern "C" void kernel_launch(void* const* d_in, const int* in_sizes, int n_in,
                              void* d_out, int out_size, void* d_ws, size_t ws_size,
                              hipStream_t stream) {
    const float* x    = (const float*)d_in[0];
    const int*   mask = (const int*)  d_in[1];
    const float* pe   = (const float*)d_in[2];
    const float* Wq   = (const float*)d_in[3];
    const float* bq   = (const float*)d_in[4];
    const float* Wk   = (const float*)d_in[5];
    const float* bk   = (const float*)d_in[6];
    const float* Wv   = (const float*)d_in[7];
    const float* bv   = (const float*)d_in[8];
    const float* Wa   = (const float*)d_in[9];
    const float* ba   = (const float*)d_in[10];
    const float* ratt = (const float*)d_in[11];
    const float* rmsg = (const float*)d_in[12];
    float* out = (float*)d_out;

    const size_t PLANE = (size_t)LAG * HW * CD;   // 22,528,000 elems

    unsigned short* qws   = (unsigned short*)d_ws;          // [pix][5][256]
    unsigned short* kws   = qws + PLANE;                    // [5][pix][256]
    unsigned short* vws   = kws + PLANE;
    unsigned short* aws   = vws + PLANE;                    // [pix][5][256]
    unsigned short* Wt    = aws + PLANE;    // 786,432 elems
    unsigned short* rattT = Wt + 786432;    // 73,728 elems
    unsigned short* rmsgT = rattT + 73728;  // 73,728 elems
    // total ~182 MB

    convert_w_kernel<<<dim3(16, 12), 256, 0, stream>>>(Wq, Wk, Wv, Wa, Wt);
    convert_rel_kernel<<<dim3(9, 8), 256, 0, stream>>>(ratt, rmsg, rattT, rmsgT);

    gemm_qkv_mfma<<<dim3(HW / 64, 1, LAG), 256, 0, stream>>>(
        x, pe, Wt, bq, bk, bv, qws, kws, vws);

    attn_fused_kernel<<<dim3(HW / 64, NHEAD), 256, 0, stream>>>(
        qws, kws, vws, rattT, rmsgT, mask, pe, aws);

    gemm_out_mfma<<<dim3(HW / 64, 1, LAG), 256, 0, stream>>>(aws, pe, Wt, ba, out);
}

// Round 17
// 184.742 us; speedup vs baseline: 1.6524x; 1.0073x over previous
//
#include <hip/hip_runtime.h>
#include <math.h>

#define HW     17600   // 100*176 pixels
#define CD     256     // channels == D
#define LAG    5       // agents
#define NHEAD  8
#define DH     32
#define NT     3       // agent types

typedef short bf16x8 __attribute__((ext_vector_type(8)));
typedef float f32x4  __attribute__((ext_vector_type(4)));

// ---- bf16 helpers ----------------------------------------------------------
__device__ __forceinline__ float bflo(unsigned u) { return __uint_as_float(u << 16); }
__device__ __forceinline__ float bfhi(unsigned u) { return __uint_as_float(u & 0xffff0000u); }
__device__ __forceinline__ unsigned f2bf(float f) {
    unsigned u = __float_as_uint(f);
    return (u + 0x7fffu + ((u >> 16) & 1u)) >> 16;   // RNE
}
__device__ __forceinline__ unsigned pack2(float a, float b) {
    return f2bf(a) | (f2bf(b) << 16);
}

// ---- async global->LDS (16B/lane); dest = wave-uniform base + lane*16 ------
typedef __attribute__((address_space(1))) const unsigned int gu32;
typedef __attribute__((address_space(3))) unsigned int       lu32;
__device__ __forceinline__ void gload_lds16(const void* g, void* l) {
    __builtin_amdgcn_global_load_lds(
        (gu32*)(unsigned long long)(uintptr_t)g,
        (lu32*)(unsigned int)(uintptr_t)l, 16, 0, 0);
}

// ---------------------------------------------------------------------------
// convert_w: W[k][n] fp32 -> Wt[n][k] bf16, 12 matrices (q0..2,k0..2,v0..2,a0..2)
// ---------------------------------------------------------------------------
__global__ __launch_bounds__(256) void convert_w_kernel(
    const float* __restrict__ Wq, const float* __restrict__ Wk,
    const float* __restrict__ Wv, const float* __restrict__ Wa,
    unsigned short* __restrict__ Wt)
{
    __shared__ float tile[64][65];
    const int mat = blockIdx.y;
    const int k0 = (blockIdx.x >> 2) * 64;
    const int n0 = (blockIdx.x & 3) * 64;
    const float* W;
    if      (mat < 3) W = Wq + (long)mat * 65536;
    else if (mat < 6) W = Wk + (long)(mat - 3) * 65536;
    else if (mat < 9) W = Wv + (long)(mat - 6) * 65536;
    else              W = Wa + (long)(mat - 9) * 65536;
    const int t = threadIdx.x;
#pragma unroll
    for (int r = 0; r < 16; ++r) {
        int idx = r * 256 + t;
        int row = idx >> 6, col = idx & 63;
        tile[row][col] = W[(long)(k0 + row) * 256 + n0 + col];
    }
    __syncthreads();
    unsigned short* dst = Wt + (long)mat * 65536;
#pragma unroll
    for (int r = 0; r < 16; ++r) {
        int idx = r * 256 + t;
        int row = idx >> 6, col = idx & 63;
        dst[(long)(n0 + row) * 256 + k0 + col] = (unsigned short)f2bf(tile[col][row]);
    }
}

// ---------------------------------------------------------------------------
// convert_rel: rel_att -> rattT bf16 [9][8][32 q][32 p] (transposed),
//              rel_msg -> rmsgT bf16 [9][8][32 c][32 p] (transposed).
// ---------------------------------------------------------------------------
__global__ __launch_bounds__(256) void convert_rel_kernel(
    const float* __restrict__ rel_att, const float* __restrict__ rel_msg,
    unsigned short* __restrict__ rattT, unsigned short* __restrict__ rmsgT)
{
    const long base = ((long)(blockIdx.x * NHEAD + blockIdx.y)) << 10;
    const int t = threadIdx.x;
#pragma unroll
    for (int i = 0; i < 4; ++i) {
        int idx = t * 4 + i;            // p*32+q
        int p = idx >> 5, q = idx & 31;
        rattT[base + q * 32 + p] = (unsigned short)f2bf(rel_att[base + idx]);
        rmsgT[base + q * 32 + p] = (unsigned short)f2bf(rel_msg[base + idx]);
    }
}

// ---------------------------------------------------------------------------
// MFMA GEMM core (64-row tile): Y[64 x 256] = A @ Wt^T + bias.
// 256 threads = 4 waves. Staging via global_load_lds (16B) with PRE-SWIZZLED
// global source; LDS dest linear. A path: fp32 (qkv) VGPR-convert staging;
// bf16 (out) gload_lds. XOR swizzle col ^= (row&7)<<3 on store + frag read.
// m0 passed by caller (grid-order freedom for dispatch locality).
// ---------------------------------------------------------------------------
template<bool AF32, bool YBF>
__device__ __forceinline__ void gemm_mfma_core(
    const void* __restrict__ Aptr, long lda,
    const unsigned short* __restrict__ Wt,
    const float* __restrict__ bias,
    void* __restrict__ Yptr, long ldy, int m0)
{
    __shared__ unsigned short As[64 * 64];
    __shared__ unsigned short Ws[256 * 64];

    const int t  = threadIdx.x;
    const int w  = t >> 6;
    const int l  = t & 63;
    const int wr = w >> 1;
    const int wc = w & 1;
    const int fr = l & 15;
    const int ko = (l >> 4) << 3;

    const int srow = t >> 3;                      // 0..31 within a round
    const int colu = (t & 7) << 3;
    const int axor = (fr & 7) << 3;

    f32x4 acc[2][8];
#pragma unroll
    for (int i = 0; i < 2; ++i)
#pragma unroll
        for (int j = 0; j < 8; ++j) {
            acc[i][j][0] = 0.f; acc[i][j][1] = 0.f;
            acc[i][j][2] = 0.f; acc[i][j][3] = 0.f;
        }

    for (int ks = 0; ks < 4; ++ks) {
        const int k0 = ks << 6;
        __syncthreads();
        // ---- stage A: 64 rows x 64 cols, 2 rounds -------------------------
#pragma unroll
        for (int r = 0; r < 2; ++r) {
            const int row  = r * 32 + srow;
            const int xr   = (row & 7) << 3;
            const int scol = colu ^ xr;
            if (AF32) {
                const float* src = (const float*)Aptr + (long)(m0 + row) * lda + k0 + colu;
                float4 f0 = *(const float4*)src;
                float4 f1 = *(const float4*)(src + 4);
                uint4 u;
                u.x = pack2(f0.x, f0.y); u.y = pack2(f0.z, f0.w);
                u.z = pack2(f1.x, f1.y); u.w = pack2(f1.z, f1.w);
                *(uint4*)(&As[row * 64 + scol]) = u;
            } else {
                const unsigned short* src =
                    (const unsigned short*)Aptr + (long)(m0 + row) * lda + k0 + scol;
                gload_lds16(src, &As[r * 2048 + w * 512]);
            }
        }
        // ---- stage Wt: 256 rows x 64 cols, 8 rounds, async ----------------
#pragma unroll
        for (int r = 0; r < 8; ++r) {
            const int row  = r * 32 + srow;
            const int scol = colu ^ ((row & 7) << 3);
            const unsigned short* src = Wt + (long)row * 256 + k0 + scol;
            gload_lds16(src, &Ws[r * 2048 + w * 512]);
        }
        __syncthreads();   // drains vmcnt (incl. global_load_lds) + lgkmcnt
#pragma unroll
        for (int kk = 0; kk < 2; ++kk) {
            const int fcol = ((kk << 5) | ko) ^ axor;
            bf16x8 a[2], b[8];
#pragma unroll
            for (int i = 0; i < 2; ++i)
                a[i] = *(const bf16x8*)(&As[(wr * 32 + i * 16 + fr) * 64 + fcol]);
#pragma unroll
            for (int j = 0; j < 8; ++j)
                b[j] = *(const bf16x8*)(&Ws[(wc * 128 + j * 16 + fr) * 64 + fcol]);
#pragma unroll
            for (int i = 0; i < 2; ++i)
#pragma unroll
                for (int j = 0; j < 8; ++j)
                    acc[i][j] = __builtin_amdgcn_mfma_f32_16x16x32_bf16(
                        a[i], b[j], acc[i][j], 0, 0, 0);
        }
    }

    const int fq = l >> 4;
#pragma unroll
    for (int j = 0; j < 8; ++j) {
        int col = wc * 128 + j * 16 + fr;
        float bz = bias[col];
#pragma unroll
        for (int i = 0; i < 2; ++i) {
            int rowb = m0 + wr * 32 + i * 16 + (fq << 2);
#pragma unroll
            for (int e = 0; e < 4; ++e) {
                float v = acc[i][j][e] + bz;
                if (YBF)
                    ((unsigned short*)Yptr)[(long)(rowb + e) * ldy + col] =
                        (unsigned short)f2bf(v);
                else
                    ((float*)Yptr)[(long)(rowb + e) * ldy + col] = v;
            }
        }
    }
}

// ---------------------------------------------------------------------------
// Kernel 1: fused q/k/v projections. grid (5, 1, 275): lag FASTEST so the 5
// writers of each interleaved q line dispatch together (write coalescing in
// L2); proj loop in-block keeps the x panel L2-hot for the 2nd/3rd pass.
// q -> [pix][5][256]; k,v -> [l][pix][256].
// ---------------------------------------------------------------------------
__global__ __launch_bounds__(256) void gemm_qkv_mfma(
    const float* __restrict__ x, const float* __restrict__ pe,
    const unsigned short* __restrict__ Wt,
    const float* __restrict__ bq, const float* __restrict__ bk,
    const float* __restrict__ bv,
    unsigned short* __restrict__ qws, unsigned short* __restrict__ kws,
    unsigned short* __restrict__ vws)
{
    const int lag = blockIdx.x;
    const int m0  = blockIdx.z * 64;
    const int tpe = (int)pe[lag * 3 + 2];
    const float* A = x + (long)lag * HW * CD;

#pragma unroll 1
    for (int proj = 0; proj < 3; ++proj) {
        const unsigned short* Wm = Wt + (long)(proj * 3 + tpe) * 65536;
        const float* bias;
        unsigned short* Y;
        long ldy;
        if      (proj == 0) { bias = bq; Y = qws + (long)lag * CD; ldy = LAG * CD; }
        else if (proj == 1) { bias = bk; Y = kws + (long)lag * HW * CD; ldy = CD; }
        else                { bias = bv; Y = vws + (long)lag * HW * CD; ldy = CD; }
        bias += tpe * CD;
        gemm_mfma_core<true, true>(A, CD, Wm, bias, Y, ldy, m0);
        __syncthreads();
    }
}

// ---------------------------------------------------------------------------
// Kernel 3: output projection. grid (5, 1, 275): lag fastest -> the 5 readers
// of each interleaved aws line dispatch together (read locality in L2).
// ---------------------------------------------------------------------------
__global__ __launch_bounds__(256) void gemm_out_mfma(
    const unsigned short* __restrict__ aws, const float* __restrict__ pe,
    const unsigned short* __restrict__ Wt, const float* __restrict__ ba,
    float* __restrict__ out)
{
    const int lag = blockIdx.x;
    const int m0  = blockIdx.z * 64;
    const int tpe = (int)pe[lag * 3 + 2];
    const unsigned short* A = aws + (long)lag * CD;
    const unsigned short* Wm = Wt + (long)(9 + tpe) * 65536;
    const float* bias = ba + tpe * CD;
    float* Y = out + (long)lag * HW * CD;
    gemm_mfma_core<false, false>(A, (long)LAG * CD, Wm, bias, Y, CD, m0);
}

// ---------------------------------------------------------------------------
// Kernel 2 (FUSED attention v5 = v1 + bpermute phase-3): measured best.
// grid (8, 275): head FASTEST so the 8 blocks sharing one 64-pixel q/k/v
// window dispatch together (L2/L3 temporal locality).
// Phase 1: qt[i][sigma] for ALL sigma via MFMA -> LDS (row 488). One barrier.
// Phase 2: logits (8-FMA dots + quad shfl), masked softmax in registers.
// Phase 3: vagg -> A-frag redistribution via 4x ds_bpermute. NO barriers.
// ---------------------------------------------------------------------------
#define QTROW 488   // 5*3*32 = 480 + 8 pad (2-way banks)

__global__ __launch_bounds__(256) void attn_fused_kernel(
    const unsigned short* __restrict__ qws,    // [pix][5][256]
    const unsigned short* __restrict__ kws,    // [j][pix][256]
    const unsigned short* __restrict__ vws,    // [j][pix][256]
    const unsigned short* __restrict__ rattT,  // [9][8][32 q][32 p]
    const unsigned short* __restrict__ rmsgT,  // [9][8][32 c][32 p]
    const int* __restrict__ mask, const float* __restrict__ pe,
    unsigned short* __restrict__ aws)          // [pix][5][256]
{
    __shared__ unsigned short lds[4 * 16 * QTROW];   // 62.5 KB

    const int t    = threadIdx.x;
    const int w    = t >> 6;
    const int l    = t & 63;
    const int fr   = l & 15;
    const int fq   = l >> 4;
    const int m    = blockIdx.x;           // head fastest
    const int pix0 = blockIdx.y * 64;

    const int pl2   = t >> 2;          // 0..63 local pixel
    const int sub   = t & 3;           // q/p octet
    const int gpix2 = pix0 + pl2;

    int ty[LAG];
#pragma unroll
    for (int i = 0; i < LAG; ++i) ty[i] = (int)pe[i * 3 + 2];
    bool pres[NT] = {false, false, false};
#pragma unroll
    for (int i = 0; i < LAG; ++i) {
        pres[0] = pres[0] || (ty[i] == 0);
        pres[1] = pres[1] || (ty[i] == 1);
        pres[2] = pres[2] || (ty[i] == 2);
    }

    // ---- early global loads (k, v, mask) for MLP --------------------------
    uint4 kf[LAG], vf[LAG];
    int mk[LAG];
#pragma unroll
    for (int j = 0; j < LAG; ++j) {
        const long off = ((long)j * HW + gpix2) * CD + m * DH + sub * 8;
        kf[j] = *(const uint4*)(kws + off);
        vf[j] = *(const uint4*)(vws + off);
        mk[j] = mask[gpix2 * LAG + j];
    }

    // ---- phase 1: qt via MFMA ---------------------------------------------
    {
        bf16x8 aq[LAG];
#pragma unroll
        for (int i = 0; i < LAG; ++i)
            aq[i] = *(const bf16x8*)(qws + (long)(pix0 + w * 16 + fr) * (LAG * CD)
                                     + i * CD + m * DH + fq * 8);
        const int qtbase = w * 16 * QTROW;
#pragma unroll
        for (int sg = 0; sg < NT; ++sg) {
            if (!pres[sg]) continue;
#pragma unroll
            for (int i = 0; i < LAG; ++i) {
                const int e = ty[i] * NT + sg;
                const unsigned short* bb = rattT + ((long)(e * NHEAD + m) << 10);
                bf16x8 b0 = *(const bf16x8*)(bb + fr * 32 + fq * 8);
                bf16x8 b1 = *(const bf16x8*)(bb + (fr + 16) * 32 + fq * 8);
                f32x4 z = {0.f, 0.f, 0.f, 0.f};
                f32x4 d0 = __builtin_amdgcn_mfma_f32_16x16x32_bf16(aq[i], b0, z, 0, 0, 0);
                f32x4 d1 = __builtin_amdgcn_mfma_f32_16x16x32_bf16(aq[i], b1, z, 0, 0, 0);
#pragma unroll
                for (int e4 = 0; e4 < 4; ++e4) {
                    const int idx = qtbase + (fq * 4 + e4) * QTROW + (i * NT + sg) * 32;
                    lds[idx + fr]      = (unsigned short)f2bf(d0[e4]);
                    lds[idx + fr + 16] = (unsigned short)f2bf(d1[e4]);
                }
            }
        }
    }
    __syncthreads();

    // ---- phase 2: logits + softmax -----------------------------------------
    const float scale = 0.17677669529663687f;  // 32^-0.5
    float att[LAG][LAG];
    {
        const int qtb = w * 16 * QTROW + (pl2 & 15) * QTROW;
#pragma unroll
        for (int j = 0; j < LAG; ++j) {
            float kx[8];
            kx[0] = bflo(kf[j].x); kx[1] = bfhi(kf[j].x);
            kx[2] = bflo(kf[j].y); kx[3] = bfhi(kf[j].y);
            kx[4] = bflo(kf[j].z); kx[5] = bfhi(kf[j].z);
            kx[6] = bflo(kf[j].w); kx[7] = bfhi(kf[j].w);
            const int tyj = ty[j];
#pragma unroll
            for (int i = 0; i < LAG; ++i) {
                uint4 qv = *(const uint4*)(&lds[qtb + (i * NT + tyj) * 32 + sub * 8]);
                float part;
                part = bflo(qv.x) * kx[0];
                part = fmaf(bfhi(qv.x), kx[1], part);
                part = fmaf(bflo(qv.y), kx[2], part);
                part = fmaf(bfhi(qv.y), kx[3], part);
                part = fmaf(bflo(qv.z), kx[4], part);
                part = fmaf(bfhi(qv.z), kx[5], part);
                part = fmaf(bflo(qv.w), kx[6], part);
                part = fmaf(bfhi(qv.w), kx[7], part);
                part += __shfl_xor(part, 1);
                part += __shfl_xor(part, 2);
                att[i][j] = part * scale;
            }
        }
#pragma unroll
        for (int i = 0; i < LAG; ++i) {
            float mx = -INFINITY;
#pragma unroll
            for (int j = 0; j < LAG; ++j) {
                att[i][j] = mk[j] ? att[i][j] : -INFINITY;
                mx = fmaxf(mx, att[i][j]);
            }
            float ssum = 0.f;
#pragma unroll
            for (int j = 0; j < LAG; ++j) {
                att[i][j] = __expf(att[i][j] - mx);
                ssum += att[i][j];
            }
            float inv = 1.f / ssum;
#pragma unroll
            for (int j = 0; j < LAG; ++j) att[i][j] *= inv;
        }
    }

    // unpack v once
    float vx[LAG][8];
#pragma unroll
    for (int j = 0; j < LAG; ++j) {
        vx[j][0] = bflo(vf[j].x); vx[j][1] = bfhi(vf[j].x);
        vx[j][2] = bflo(vf[j].y); vx[j][3] = bfhi(vf[j].y);
        vx[j][4] = bflo(vf[j].z); vx[j][5] = bfhi(vf[j].z);
        vx[j][6] = bflo(vf[j].w); vx[j][7] = bfhi(vf[j].w);
    }

    // ---- phase 3: vagg -> ds_bpermute redistribution -> MFMA ---------------
    f32x4 oacc[LAG][2];
#pragma unroll
    for (int i = 0; i < LAG; ++i)
#pragma unroll
        for (int c = 0; c < 2; ++c) {
            oacc[i][c][0] = 0.f; oacc[i][c][1] = 0.f;
            oacc[i][c][2] = 0.f; oacc[i][c][3] = 0.f;
        }

    const int baddr = (((l & 15) << 2) | (l >> 4)) << 2;

#pragma unroll
    for (int sg = 0; sg < NT; ++sg) {
        if (!pres[sg]) continue;
#pragma unroll
        for (int i = 0; i < LAG; ++i) {
            float vg[8] = {0.f,0.f,0.f,0.f,0.f,0.f,0.f,0.f};
#pragma unroll
            for (int j = 0; j < LAG; ++j) {
                float wj = (ty[j] == sg) ? att[i][j] : 0.f;
#pragma unroll
                for (int d = 0; d < 8; ++d) vg[d] = fmaf(wj, vx[j][d], vg[d]);
            }
            int p0 = (int)pack2(vg[0], vg[1]);
            int p1 = (int)pack2(vg[2], vg[3]);
            int p2 = (int)pack2(vg[4], vg[5]);
            int p3 = (int)pack2(vg[6], vg[7]);
            int r0 = __builtin_amdgcn_ds_bpermute(baddr, p0);
            int r1 = __builtin_amdgcn_ds_bpermute(baddr, p1);
            int r2 = __builtin_amdgcn_ds_bpermute(baddr, p2);
            int r3 = __builtin_amdgcn_ds_bpermute(baddr, p3);
            int av[4] = {r0, r1, r2, r3};
            bf16x8 a = *(const bf16x8*)av;

            const int e = ty[i] * NT + sg;
            const unsigned short* bb = rmsgT + ((long)(e * NHEAD + m) << 10);
            bf16x8 b0 = *(const bf16x8*)(bb + fr * 32 + fq * 8);
            bf16x8 b1 = *(const bf16x8*)(bb + (fr + 16) * 32 + fq * 8);
            oacc[i][0] = __builtin_amdgcn_mfma_f32_16x16x32_bf16(a, b0, oacc[i][0], 0, 0, 0);
            oacc[i][1] = __builtin_amdgcn_mfma_f32_16x16x32_bf16(a, b1, oacc[i][1], 0, 0, 0);
        }
    }

    // ---- store: lane holds out[pix=fq*4+e][c=fr, fr+16] --------------------
#pragma unroll
    for (int i = 0; i < LAG; ++i) {
#pragma unroll
        for (int e4 = 0; e4 < 4; ++e4) {
            const long ob = (long)(pix0 + w * 16 + fq * 4 + e4) * (LAG * CD)
                            + i * CD + m * DH;
            aws[ob + fr]      = (unsigned short)f2bf(oacc[i][0][e4]);
            aws[ob + fr + 16] = (unsigned short)f2bf(oacc[i][1][e4]);
        }
    }
}

// ---------------------------------------------------------------------------
extern "C" void kernel_launch(void* const* d_in, const int* in_sizes, int n_in,
                              void* d_out, int out_size, void* d_ws, size_t ws_size,
                              hipStream_t stream) {
    const float* x    = (const float*)d_in[0];
    const int*   mask = (const int*)  d_in[1];
    const float* pe   = (const float*)d_in[2];
    const float* Wq   = (const float*)d_in[3];
    const float* bq   = (const float*)d_in[4];
    const float* Wk   = (const float*)d_in[5];
    const float* bk   = (const float*)d_in[6];
    const float* Wv   = (const float*)d_in[7];
    const float* bv   = (const float*)d_in[8];
    const float* Wa   = (const float*)d_in[9];
    const float* ba   = (const float*)d_in[10];
    const float* ratt = (const float*)d_in[11];
    const float* rmsg = (const float*)d_in[12];
    float* out = (float*)d_out;

    const size_t PLANE = (size_t)LAG * HW * CD;   // 22,528,000 elems

    unsigned short* qws   = (unsigned short*)d_ws;          // [pix][5][256]
    unsigned short* kws   = qws + PLANE;                    // [5][pix][256]
    unsigned short* vws   = kws + PLANE;
    unsigned short* aws   = vws + PLANE;                    // [pix][5][256]
    unsigned short* Wt    = aws + PLANE;    // 786,432 elems
    unsigned short* rattT = Wt + 786432;    // 73,728 elems
    unsigned short* rmsgT = rattT + 73728;  // 73,728 elems
    // total ~182 MB

    convert_w_kernel<<<dim3(16, 12), 256, 0, stream>>>(Wq, Wk, Wv, Wa, Wt);
    convert_rel_kernel<<<dim3(9, 8), 256, 0, stream>>>(ratt, rmsg, rattT, rmsgT);

    gemm_qkv_mfma<<<dim3(LAG, 1, HW / 64), 256, 0, stream>>>(
        x, pe, Wt, bq, bk, bv, qws, kws, vws);

    attn_fused_kernel<<<dim3(NHEAD, HW / 64), 256, 0, stream>>>(
        qws, kws, vws, rattT, rmsgT, mask, pe, aws);

    gemm_out_mfma<<<dim3(LAG, 1, HW / 64), 256, 0, stream>>>(aws, pe, Wt, ba, out);
}